// Round 10
// baseline (4141.866 us; speedup 1.0000x reference)
//
#include <hip/hip_runtime.h>

typedef _Float16 half2_t __attribute__((ext_vector_type(2)));
typedef __bf16   bf16x8  __attribute__((ext_vector_type(8)));
typedef float    f32x4   __attribute__((ext_vector_type(4)));
typedef unsigned short u16x8 __attribute__((ext_vector_type(8)));
typedef unsigned int  uint32;
typedef unsigned long long uint64;

#define LSTM_N 32
#define LSTM_T 2048
#define LSTM_D 256
#define LSTM_H 256
#define NG 1024
#define CH 256                    // time-chunk length
#define NCH (LSTM_T / CH)         // 8 chunks
#define MCH (LSTM_N * CH)         // 8192 rows per chunk GEMM

// ---- workspace layout (bytes) ---- (~35.2 MB)
#define OFF_XG   ((size_t)0)
#define SZ_XG    ((size_t)MCH * NG * 4)             // 33,554,432 xg chunk f32
#define OFF_WIHB (OFF_XG + SZ_XG)
#define SZ_WIHB  ((size_t)NG * LSTM_D * 2)          // w_ih bf16
#define OFF_BIAS (OFF_WIHB + SZ_WIHB)
#define SZ_BIAS  ((size_t)4096)
#define OFF_WPK  (OFF_BIAS + SZ_BIAS)
#define SZ_WPK   ((size_t)2 * 512 * 128 * 4)        // 524,288 w_hh f16 pairs (k-split layout)
#define OFF_CST  (OFF_WPK + SZ_WPK)
#define SZ_CST   ((size_t)LSTM_N * 256 * 4)         // c state f32
#define OFF_HST  (OFF_CST + SZ_CST)
#define SZ_HST   ((size_t)LSTM_N * 128 * 4)         // h state f16-pairs (u32)
#define OFF_HPX  (OFF_HST + SZ_HST)
#define SZ_HPX   ((size_t)LSTM_N * 2 * 1024 * 8)    // 524,288 tagged-u64 partial slots

#if defined(__has_builtin)
#if __has_builtin(__builtin_amdgcn_fdot2)
#define HAVE_FDOT2 1
#endif
#endif

// PROVEN datapath (R2/R3/R6/R8/R9, absmax 0.0078). Inline-asm v_dot2 is
// numerically WRONG on gfx950 (R5/R7 failed identically) - permanently banned.
__device__ __forceinline__ float fdot2(uint32 w, uint32 h, float acc) {
#ifdef HAVE_FDOT2
  return __builtin_amdgcn_fdot2(__builtin_bit_cast(half2_t, w),
                                __builtin_bit_cast(half2_t, h), acc, false);
#else
  half2_t wv = __builtin_bit_cast(half2_t, w);
  half2_t hv = __builtin_bit_cast(half2_t, h);
  float r = fmaf((float)wv.x, (float)hv.x, acc);
  return fmaf((float)wv.y, (float)hv.y, r);
#endif
}

__device__ __forceinline__ float sigm(float x) { return 1.f / (1.f + __expf(-x)); }
__device__ __forceinline__ float tanh_fast(float x) { return 2.f / (1.f + __expf(-2.f * x)) - 1.f; }

__device__ __forceinline__ unsigned short f2bf(float f) {
  uint32 u = __builtin_bit_cast(uint32, f);
  uint32 r = (u + 0x7FFFu + ((u >> 16) & 1u)) >> 16;
  return (unsigned short)r;
}

// ---------------- kernels ----------------

__global__ void cvt_bf16_k(const float* __restrict__ src, unsigned short* __restrict__ dst, int n) {
  int i = blockIdx.x * blockDim.x + threadIdx.x;
  if (4 * i + 3 < n) {
    float4 v = ((const float4*)src)[i];
    ushort4 o;
    o.x = f2bf(v.x); o.y = f2bf(v.y); o.z = f2bf(v.z); o.w = f2bf(v.w);
    ((ushort4*)dst)[i] = o;
  }
}

__global__ void bias_sum_k(const float* __restrict__ bih, const float* __restrict__ bhh,
                           float* __restrict__ bias) {
  int g = blockIdx.x * blockDim.x + threadIdx.x;
  if (g < NG) bias[g] = bih[g] + bhh[g];
}

// Pack w_hh f32[1024][256] -> k-split f16-pair images.
// Scan WG p, thread t owns rows {t, t+512} over k in [128p, 128p+128).
// Element i = rh*64 + jj (rh: row-half, jj: k-pair): row = t + rh*512,
// k = 128p + 2jj. Stored so scan's uint4 ig-load is coalesced over t.
__global__ void wpack_k(const float* __restrict__ whh, uint32* __restrict__ wpk) {
  int e = blockIdx.x * blockDim.x + threadIdx.x;  // < 131072
  int p = e >> 16;
  int i = (e >> 9) & 127;
  int t = e & 511;
  int rh = i >> 6, jj = i & 63;
  int row = t + rh * 512;
  int k = 128 * p + 2 * jj;
  half2_t h;
  h.x = (_Float16)whh[row * 256 + k];
  h.y = (_Float16)whh[row * 256 + k + 1];
  wpk[((i >> 2) * 1024 + p * 512 + t) * 4 + (i & 3)] = __builtin_bit_cast(uint32, h);
}

// init carried state + zero partial-exchange tags (every launch -> replay-safe)
__global__ void state_init_k(const float* __restrict__ state, float* __restrict__ cst,
                             uint32* __restrict__ hst, uint64* __restrict__ hpx) {
  int i = blockIdx.x * blockDim.x + threadIdx.x;  // < 8192
  int n = i >> 8, j = i & 255;
  cst[i] = state[n * 512 + 256 + j];
  if ((j & 1) == 0) {
    half2_t h2;
    h2.x = (_Float16)state[n * 512 + j];
    h2.y = (_Float16)state[n * 512 + j + 1];
    hst[(n << 7) + (j >> 1)] = __builtin_bit_cast(uint32, h2);
  }
#pragma unroll
  for (int z = 0; z < 8; ++z) hpx[(size_t)i * 8 + z] = 0ull;  // tags=0; first want=1
}

// xg[8192][1024] = x(chunk rows, cvt bf16 inline) @ w_ih_bf16^T + bias  [R2/R3 verbatim]
__global__ __launch_bounds__(256) void gemm_xg(const float* __restrict__ x,
                                               const unsigned short* __restrict__ wb,
                                               const float* __restrict__ bias,
                                               float* __restrict__ xg, int ch) {
  __shared__ unsigned short As[128 * 40];  // 80B rows (stride = 5*16B, odd*16)
  __shared__ unsigned short Bs[128 * 40];
  const int tid = threadIdx.x;
  const int m0 = blockIdx.y * 128;
  const int g0 = blockIdx.x * 128;
  const int w = tid >> 6;
  const int lane = tid & 63;
  const int wm = (w >> 1) * 64, wn = (w & 1) * 64;
  const int row_l = tid >> 2;  // 0..63
  const int q = tid & 3;
  const int lr = lane & 15, kg = lane >> 4;

  size_t grow[2];
#pragma unroll
  for (int r = 0; r < 2; ++r) {
    int gm = m0 + row_l + 64 * r;
    grow[r] = (size_t)(gm >> 8) * LSTM_T + (size_t)ch * CH + (gm & 255);
  }

  f32x4 acc[4][4];
#pragma unroll
  for (int i = 0; i < 4; ++i)
#pragma unroll
    for (int j = 0; j < 4; ++j) acc[i][j] = (f32x4){0.f, 0.f, 0.f, 0.f};

  for (int kt = 0; kt < 8; ++kt) {
#pragma unroll
    for (int r = 0; r < 2; ++r) {
      int row = row_l + 64 * r;
      const float* ap = x + grow[r] * 256 + kt * 32 + q * 8;
      float4 v0 = *(const float4*)ap;
      float4 v1 = *(const float4*)(ap + 4);
      u16x8 o;
      o[0] = f2bf(v0.x); o[1] = f2bf(v0.y); o[2] = f2bf(v0.z); o[3] = f2bf(v0.w);
      o[4] = f2bf(v1.x); o[5] = f2bf(v1.y); o[6] = f2bf(v1.z); o[7] = f2bf(v1.w);
      *(uint4*)((char*)As + row * 80 + q * 16) = __builtin_bit_cast(uint4, o);
      uint4 bv = *(const uint4*)(wb + (size_t)(g0 + row) * 256 + kt * 32 + q * 8);
      *(uint4*)((char*)Bs + row * 80 + q * 16) = bv;
    }
    __syncthreads();
    bf16x8 af[4], bfr[4];
#pragma unroll
    for (int i = 0; i < 4; ++i)
      af[i] = __builtin_bit_cast(bf16x8, *(const uint4*)((char*)As + (wm + 16 * i + lr) * 80 + kg * 16));
#pragma unroll
    for (int j = 0; j < 4; ++j)
      bfr[j] = __builtin_bit_cast(bf16x8, *(const uint4*)((char*)Bs + (wn + 16 * j + lr) * 80 + kg * 16));
#pragma unroll
    for (int i = 0; i < 4; ++i)
#pragma unroll
      for (int j = 0; j < 4; ++j)
        acc[i][j] = __builtin_amdgcn_mfma_f32_16x16x32_bf16(af[i], bfr[j], acc[i][j], 0, 0, 0);
    __syncthreads();
  }
#pragma unroll
  for (int j = 0; j < 4; ++j) {
    int gc = g0 + wn + 16 * j + lr;
    float bj = bias[gc];
#pragma unroll
    for (int i = 0; i < 4; ++i) {
#pragma unroll
      for (int r = 0; r < 4; ++r) {
        int m = m0 + wm + 16 * i + kg * 4 + r;
        xg[(size_t)m * NG + gc] = acc[i][j][r] + bj;
      }
    }
  }
}

// Recurrent scan: 64 WGs, pair (n, n+32) k-splits one sample.
// WG p: k in [128p,128p+128) for ALL 1024 rows; h NEVER crosses WGs (dots
// consume exactly the h-half this WG's cell produces). Cross-WG traffic =
// f32 partials, posted right after dots (tagged-u64 single-atomic, R3-proven
// protocol, tag = gs+1, parity dbuf, s_sleep back-off spin).
// Thread t: rows {t, t+512}; v=t&255; own half iff (v>>7)==p. Own threads
// finalize (add peer partial + xg, act); peer threads post. Cell by the 128
// own threads with t>>8==0. All branches wave-uniform. 2 barriers/step.
__global__ __launch_bounds__(512, 1) void lstm_scan(const float* __restrict__ xg,
                                                    const uint4* __restrict__ wpk4,
                                                    float* __restrict__ cst,
                                                    uint32* __restrict__ hst,
                                                    uint64* __restrict__ hpx,
                                                    float* __restrict__ out, int ch) {
  __shared__ float actb[512];         // own-half gates: [gate q][u]
  __shared__ uint32 hown[2][64];      // own-half h f16-pairs, parity per step
  __shared__ float ostage[16][128];   // h staging, flushed every 16 steps

  const int b = blockIdx.x;
  const int n = b & 31;
  const int p = b >> 5;
  const int t = threadIdx.x;
  const int q1 = t >> 8;              // gate of row1 (0 or 1); row2 gate = q1+2
  const int v = t & 255;
  const int u = v & 127;
  const bool own = ((v >> 7) == p);   // wave-uniform
  const bool iscell = own && (q1 == 0);
  const int r1 = t, r2 = t + 512;     // global gate-row ids

  // weights -> 128 regs (AGPR split accepted; builtin fdot2 pays the copy)
  uint32 wr[128];
#pragma unroll
  for (int ig = 0; ig < 32; ++ig) {
    uint4 w4 = wpk4[ig * 1024 + p * 512 + t];
    wr[4 * ig + 0] = w4.x; wr[4 * ig + 1] = w4.y; wr[4 * ig + 2] = w4.z; wr[4 * ig + 3] = w4.w;
  }
  float c = 0.f;
  if (iscell) c = cst[n * 256 + 128 * p + u];
  if (t < 64) hown[0][t] = hst[n * 128 + 64 * p + t];
  __syncthreads();

  const float* xgn = xg + (size_t)n * CH * NG;
  float* outb = out + ((size_t)n * LSTM_T + (size_t)ch * CH) * LSTM_H;
  uint64* slots = hpx + (size_t)n * 2048;   // [parity][1024 rows]
  const int gsbase = ch * CH;

  float x1 = 0.f, x2 = 0.f;
  if (own) { x1 = xgn[r1]; x2 = xgn[r2]; }

  for (int tt = 0; tt < CH; ++tt) {
    const uint32 want = (uint32)(gsbase + tt) + 1;   // never 0 -> no init false-match
    const int par = tt & 1;
    // dots: both rows over own k-half (128 dot2; 8 chains of 16)
    float a1 = 0.f, a2 = 0.f;
    const uint32* hp = &hown[par][0];
#pragma unroll
    for (int c4 = 0; c4 < 4; ++c4) {
      uint32 hh[16];
      *(uint4*)&hh[0]  = *(const uint4*)&hp[16 * c4 + 0];
      *(uint4*)&hh[4]  = *(const uint4*)&hp[16 * c4 + 4];
      *(uint4*)&hh[8]  = *(const uint4*)&hp[16 * c4 + 8];
      *(uint4*)&hh[12] = *(const uint4*)&hp[16 * c4 + 12];
      float s1 = 0.f, s2 = 0.f;
#pragma unroll
      for (int j = 0; j < 16; ++j) {
        s1 = fdot2(wr[16 * c4 + j],      hh[j], s1);
        s2 = fdot2(wr[64 + 16 * c4 + j], hh[j], s2);
      }
      a1 += s1; a2 += s2;
    }
    if (own) {
      // spin for peer partials of rows r1, r2 (single-atomic tag+data)
      uint64 m1, m2;
      uint64* s1p = &slots[(size_t)par * 1024 + r1];
      uint64* s2p = &slots[(size_t)par * 1024 + r2];
      for (;;) {
        m1 = __hip_atomic_load(s1p, __ATOMIC_RELAXED, __HIP_MEMORY_SCOPE_AGENT);
        if ((uint32)(m1 >> 32) == want) break;
        __builtin_amdgcn_s_sleep(1);
      }
      for (;;) {
        m2 = __hip_atomic_load(s2p, __ATOMIC_RELAXED, __HIP_MEMORY_SCOPE_AGENT);
        if ((uint32)(m2 >> 32) == want) break;
        __builtin_amdgcn_s_sleep(1);
      }
      float pre1 = a1 + __builtin_bit_cast(float, (uint32)m1) + x1;
      float pre2 = a2 + __builtin_bit_cast(float, (uint32)m2) + x2;
      if (tt < CH - 1) {  // prefetch next step's xg
        x1 = xgn[(size_t)(tt + 1) * NG + r1];
        x2 = xgn[(size_t)(tt + 1) * NG + r2];
      }
      float g1 = sigm(pre1);                                  // gates i/f: sigmoid
      float g2 = (q1 == 0) ? tanh_fast(pre2) : sigm(pre2);    // g: tanh, o: sigmoid
      actb[q1 * 128 + u] = g1;
      actb[(q1 + 2) * 128 + u] = g2;
    } else {
      // post partials for peer's rows (fire-and-forget, single-atomic)
      __hip_atomic_store(&slots[(size_t)par * 1024 + r1],
                         (uint64)__builtin_bit_cast(uint32, a1) | ((uint64)want << 32),
                         __ATOMIC_RELAXED, __HIP_MEMORY_SCOPE_AGENT);
      __hip_atomic_store(&slots[(size_t)par * 1024 + r2],
                         (uint64)__builtin_bit_cast(uint32, a2) | ((uint64)want << 32),
                         __ATOMIC_RELAXED, __HIP_MEMORY_SCOPE_AGENT);
    }
    __syncthreads();                    // BAR-A: actb ready
    if (iscell) {
      float gi = actb[u];
      float gf = actb[128 + u];
      float gg = actb[256 + u];
      float go = actb[384 + u];
      c = gf * c + gi * gg;
      float h = go * tanh_fast(c);
      _Float16 hf = (_Float16)h;
      ((unsigned short*)&hown[par ^ 1][0])[u] = __builtin_bit_cast(unsigned short, hf);
      ostage[tt & 15][u] = h;
      if (ch == NCH - 1 && tt == CH - 1) {
        float* os = out + (size_t)LSTM_N * LSTM_T * LSTM_H + n * 512;
        os[128 * p + u] = h;
        os[256 + 128 * p + u] = c;
      }
    }
    __syncthreads();                    // BAR-B: hown(next parity)/ostage visible
    if ((tt & 15) == 15) {              // flush 16 staged steps, coalesced
      int sl = t >> 5, q4 = t & 31;
      float4 vv = *(const float4*)&ostage[sl][4 * q4];
      *(float4*)&outb[(size_t)(tt - 15 + sl) * LSTM_H + 128 * p + 4 * q4] = vv;
    }
  }
  // persist carried state (CH even -> final h landed in hown[0])
  if (iscell) cst[n * 256 + 128 * p + u] = c;
  if (t < 64) hst[n * 128 + 64 * p + t] = hown[0][t];
}

extern "C" void kernel_launch(void* const* d_in, const int* in_sizes, int n_in,
                              void* d_out, int out_size, void* d_ws, size_t ws_size,
                              hipStream_t stream) {
  const float* x   = (const float*)d_in[0];
  const float* st  = (const float*)d_in[1];
  const float* wih = (const float*)d_in[2];
  const float* whh = (const float*)d_in[3];
  const float* bih = (const float*)d_in[4];
  const float* bhh = (const float*)d_in[5];
  float* out = (float*)d_out;
  char* ws = (char*)d_ws;

  float* xg = (float*)(ws + OFF_XG);
  unsigned short* wihb = (unsigned short*)(ws + OFF_WIHB);
  float* bias = (float*)(ws + OFF_BIAS);
  uint32* wpk = (uint32*)(ws + OFF_WPK);
  float* cst = (float*)(ws + OFF_CST);
  uint32* hst = (uint32*)(ws + OFF_HST);
  uint64* hpx = (uint64*)(ws + OFF_HPX);

  cvt_bf16_k<<<(NG * LSTM_D / 4 + 255) / 256, 256, 0, stream>>>(wih, wihb, NG * LSTM_D);
  bias_sum_k<<<4, 256, 0, stream>>>(bih, bhh, bias);
  wpack_k<<<512, 256, 0, stream>>>(whh, wpk);
  state_init_k<<<32, 256, 0, stream>>>(st, cst, hst, hpx);

  for (int ch = 0; ch < NCH; ++ch) {
    gemm_xg<<<dim3(NG / 128, MCH / 128), 256, 0, stream>>>(x, wihb, bias, xg, ch);
    lstm_scan<<<64, 512, 0, stream>>>(xg, (const uint4*)wpk, cst, hst, hpx, out, ch);
  }
}